// Round 4
// baseline (726.167 us; speedup 1.0000x reference)
//
#include <hip/hip_runtime.h>
#include <hip/hip_bf16.h>

#define B_ 32
#define C_ 48
#define H_ 64
#define W_ 128
#define K_ 5
#define SLAB (C_*H_*W_)
#define RS 72                 // carry row stride (bf16) = 144B
#define ROWS 132              // W_+4 halo rows
#define KB 10                 // K blocks: 5*64/32
#define WC (W_*C_)
#define HC (H_*C_)

typedef __attribute__((ext_vector_type(8))) short short8;
typedef __attribute__((ext_vector_type(4))) float f32x4;

__device__ __forceinline__ void lbar() {
  asm volatile("s_waitcnt lgkmcnt(0)\n\ts_barrier" ::: "memory");
}

__device__ __forceinline__ unsigned short f2bf(float f) {
  union { float f; unsigned u; } v; v.f = f;
  unsigned r = v.u + 0x7fffu + ((v.u >> 16) & 1u);
  return (unsigned short)(r >> 16);
}

__device__ __forceinline__ unsigned pk2(float a, float b) {
  union { __hip_bfloat162 h; unsigned u; } z;
  z.h = __float22bfloat162_rn(float2{a, b});
  return z.u;
}

// Weights as MFMA *A* operand: A[m][k'], m = mt*16 + (lane&15),
// k' = kb*32 + q*8 + j  ->  tap k = k'>>6, in-chan i = k'&63 (zero-pad 48..63).
__device__ __forceinline__ void load_wA(const float* __restrict__ wgt,
                                        const float* __restrict__ bias,
                                        short8 A[3][KB], float bv[3][4],
                                        int l15, int q) {
#pragma unroll
  for (int mt = 0; mt < 3; ++mt) {
#pragma unroll
    for (int r = 0; r < 4; ++r) bv[mt][r] = bias[mt * 16 + 4 * q + r];
#pragma unroll
    for (int kb = 0; kb < KB; ++kb) {
      short8 f;
#pragma unroll
      for (int j = 0; j < 8; ++j) {
        int kp = kb * 32 + q * 8 + j, k = kp >> 6, i = kp & 63;
        f[j] = (i < C_) ? (short)f2bf(wgt[(mt * 16 + l15) * (C_ * K_) + i * K_ + k])
                        : (short)0;
      }
      A[mt][kb] = f;
    }
  }
}

template<int NTW>
__device__ __forceinline__ void load_xin(float4 xv[NTW][3], const float* __restrict__ inp,
                                         int lRS, int n0, int l15, int c0) {
#pragma unroll
  for (int nt = 0; nt < NTW; ++nt) {
    const float* p = inp + (size_t)(n0 + nt * 16 + l15) * lRS;
#pragma unroll
    for (int mt = 0; mt < 3; ++mt)
      xv[nt][mt] = *(const float4*)(p + mt * 16 + c0);
  }
}

template<int NTW>
__device__ __forceinline__ void do_step(const unsigned short* __restrict__ scr,
                                        unsigned short* __restrict__ scw,
                                        const short8 A[3][KB], const float bv[3][4],
                                        const float4 xv[NTW][3],
                                        float* __restrict__ outp,
                                        int n0, int l15, int q, int c0) {
  f32x4 acc[NTW][3];
#pragma unroll
  for (int nt = 0; nt < NTW; ++nt)
#pragma unroll
    for (int mt = 0; mt < 3; ++mt) acc[nt][mt] = (f32x4){0.f, 0.f, 0.f, 0.f};

#pragma unroll
  for (int kb = 0; kb < KB; ++kb) {
    short8 pf[NTW];
#pragma unroll
    for (int nt = 0; nt < NTW; ++nt)
      pf[nt] = *(const short8*)(scr + (size_t)(n0 + nt * 16 + l15 + (kb >> 1)) * RS
                                + (kb & 1) * 32 + q * 8);
#pragma unroll
    for (int nt = 0; nt < NTW; ++nt)
#pragma unroll
      for (int mt = 0; mt < 3; ++mt)
        acc[nt][mt] = __builtin_amdgcn_mfma_f32_16x16x32_bf16(A[mt][kb], pf[nt],
                                                              acc[nt][mt], 0, 0, 0);
  }

#pragma unroll
  for (int nt = 0; nt < NTW; ++nt) {
    const int row = n0 + nt * 16 + l15;
#pragma unroll
    for (int mt = 0; mt < 3; ++mt) {
      float4 v;
      v.x = acc[nt][mt][0] + xv[nt][mt].x + bv[mt][0];
      v.y = acc[nt][mt][1] + xv[nt][mt].y + bv[mt][1];
      v.z = acc[nt][mt][2] + xv[nt][mt].z + bv[mt][2];
      v.w = acc[nt][mt][3] + xv[nt][mt].w + bv[mt][3];
      *(float4*)(outp + (size_t)row * C_ + mt * 16 + c0) = v;
      uint2 pk; pk.x = pk2(v.x, v.y); pk.y = pk2(v.z, v.w);
      *(uint2*)(scw + (size_t)(row + 2) * RS + mt * 16 + c0) = pk;
    }
  }
  lbar();
}

template<int NTW>
__device__ __forceinline__ void init_store(unsigned short* __restrict__ scw,
                                           const float* __restrict__ inp, int lRS,
                                           float* __restrict__ outp,
                                           int n0, int l15, int q, int c0) {
  float4 xv[NTW][3];
  load_xin<NTW>(xv, inp, lRS, n0, l15, c0);
#pragma unroll
  for (int nt = 0; nt < NTW; ++nt) {
    const int row = n0 + nt * 16 + l15;
#pragma unroll
    for (int mt = 0; mt < 3; ++mt) {
      float4 v = xv[nt][mt];
      *(float4*)(outp + (size_t)row * C_ + mt * 16 + c0) = v;
      uint2 pk; pk.x = pk2(v.x, v.y); pk.y = pk2(v.z, v.w);
      *(uint2*)(scw + (size_t)(row + 2) * RS + mt * 16 + c0) = pk;
    }
  }
  lbar();
}

template<int NTW, class FIN, class FOUT>
__device__ __forceinline__ void run_pass(unsigned short* sb, int& p,
                                         const short8 A[3][KB], const float bv[3][4],
                                         int nsteps, FIN inadr, int lRS, FOUT outadr,
                                         int n0, int l15, int q, int c0) {
  float4 xa[NTW][3], xb[NTW][3];
  load_xin<NTW>(xa, inadr(1), lRS, n0, l15, c0);
  for (int s = 1; s <= nsteps; s += 2) {
    {
      int sn = (s + 1 <= nsteps) ? s + 1 : nsteps;
      load_xin<NTW>(xb, inadr(sn), lRS, n0, l15, c0);
      __builtin_amdgcn_sched_barrier(0x38F);
      do_step<NTW>(sb + (size_t)p * (ROWS * RS), sb + (size_t)(p ^ 1) * (ROWS * RS),
                   A, bv, xa, outadr(s), n0, l15, q, c0);
      p ^= 1;
    }
    if (s + 1 <= nsteps) {
      int sn = (s + 2 <= nsteps) ? s + 2 : nsteps;
      load_xin<NTW>(xa, inadr(sn), lRS, n0, l15, c0);
      __builtin_amdgcn_sched_barrier(0x38F);
      do_step<NTW>(sb + (size_t)p * (ROWS * RS), sb + (size_t)(p ^ 1) * (ROWS * RS),
                   A, bv, xb, outadr(s + 1), n0, l15, q, c0);
      p ^= 1;
    }
  }
}

// 2 batches per 512-thread block: sub-block 0 -> batch 2*bid, sub-block 1 -> 2*bid+1.
// Gives 2 waves/SIMD so the two batches' dependency chains hide each other.
__global__ __launch_bounds__(512, 1) void scnn_mfma(
    float* ws,
    const float* __restrict__ dw, const float* __restrict__ db,
    const float* __restrict__ rw, const float* __restrict__ rb,
    const float* __restrict__ lw, const float* __restrict__ lb,
    float* __restrict__ DU)
{
  __shared__ unsigned short sball[2][2 * ROWS * RS];   // 76 KB
  const int sub = threadIdx.x >> 8;
  const int tid = threadIdx.x & 255, lane = tid & 63, wid = tid >> 6;
  const int l15 = lane & 15, q = lane >> 4, c0 = 4 * q;
  const int b = blockIdx.x * 2 + sub;
  unsigned short* sb = &sball[sub][0];
  float* xbuf = ws + (size_t)b * SLAB;
  float* rl   = ws + (size_t)b * SLAB;
  float* du   = DU + (size_t)b * SLAB;
  const int n0w = wid * 32, n0h = wid * 16;

  short8 A[3][KB];
  float bv[3][4];
  int p = 0;

  // ---------------- DOWN ----------------
  load_wA(dw, db, A, bv, l15, q);
  { unsigned* z = (unsigned*)sb; for (int i = tid; i < ROWS * RS; i += 256) z[i] = 0u; }
  __syncthreads();
  init_store<2>(sb, xbuf, C_, du, n0w, l15, q, c0);
  run_pass<2>(sb, p, A, bv, H_ - 1,
              [&](int s) { return xbuf + (size_t)s * WC; }, C_,
              [&](int s) { return du + (size_t)s * WC; }, n0w, l15, q, c0);
  __syncthreads();

  // ---------------- UP (down weights; carry = D[63] persists) ----------------
  run_pass<2>(sb, p, A, bv, H_ - 1,
              [&](int s) { int ih = (s <= H_ - 2) ? (H_ - 2 - s) : (H_ - 1);
                           return du + (size_t)ih * WC; }, C_,
              [&](int s) { return du + (size_t)(H_ - 1 - s) * WC; }, n0w, l15, q, c0);
  __syncthreads();

  // ---------------- RIGHT ----------------
  load_wA(rw, rb, A, bv, l15, q);
  { unsigned* z = (unsigned*)sb; for (int i = tid; i < ROWS * RS; i += 256) z[i] = 0u; }
  __syncthreads();
  p = 0;
  init_store<1>(sb, du, WC, rl, n0h, l15, q, c0);
  run_pass<1>(sb, p, A, bv, W_ - 1,
              [&](int s) { return du + (size_t)s * C_; }, WC,
              [&](int s) { return rl + (size_t)s * HC; }, n0h, l15, q, c0);
  __syncthreads();

  // ---------------- LEFT (carry = R[127]; L[127]=R[127] already in place) ----
  load_wA(lw, lb, A, bv, l15, q);
  run_pass<1>(sb, p, A, bv, W_ - 1,
              [&](int s) { return rl + (size_t)(W_ - 1 - s) * HC; }, C_,
              [&](int s) { return rl + (size_t)(W_ - 1 - s) * HC; }, n0h, l15, q, c0);
}

// x [b][c][h][w] -> xT [b][h][w][c]
__global__ __launch_bounds__(256) void xpose_chw_hwc(const float* __restrict__ x,
                                                     float* __restrict__ xT) {
  __shared__ float t[C_ * 129];
  const int bh = blockIdx.x, b = bh >> 6, h = bh & 63;
  const float* src = x + (size_t)b * SLAB + (size_t)h * W_;
  float* dst = xT + (size_t)b * SLAB + (size_t)h * (W_ * C_);
  for (int i = threadIdx.x; i < C_ * W_; i += 256) {
    int c = i >> 7, w = i & 127;
    t[c * 129 + w] = src[(size_t)c * (H_ * W_) + w];
  }
  __syncthreads();
  for (int i = threadIdx.x; i < C_ * W_; i += 256) {
    int w = i / C_, c = i - w * C_;
    dst[i] = t[c * 129 + w];
  }
}

// L [b][w][h][c] -> out [b][c][h][w]
__global__ __launch_bounds__(256) void xpose_whc_chw(const float* __restrict__ L,
                                                     float* __restrict__ out) {
  __shared__ float t[W_ * 49];
  const int bh = blockIdx.x, b = bh >> 6, h = bh & 63;
  const float* src = L + (size_t)b * SLAB + (size_t)h * C_;
  float* dst = out + (size_t)b * SLAB + (size_t)h * W_;
  for (int i = threadIdx.x; i < W_ * C_; i += 256) {
    int w = i / C_, c = i - w * C_;
    t[w * 49 + c] = src[(size_t)w * (H_ * C_) + c];
  }
  __syncthreads();
  for (int i = threadIdx.x; i < C_ * W_; i += 256) {
    int c = i >> 7, w = i & 127;
    dst[(size_t)c * (H_ * W_) + w] = t[w * 49 + c];
  }
}

extern "C" void kernel_launch(void* const* d_in, const int* in_sizes, int n_in,
                              void* d_out, int out_size, void* d_ws, size_t ws_size,
                              hipStream_t stream) {
  const float* x  = (const float*)d_in[0];
  const float* dw = (const float*)d_in[1];
  const float* db = (const float*)d_in[2];
  const float* rw = (const float*)d_in[3];
  const float* rb = (const float*)d_in[4];
  const float* lw = (const float*)d_in[5];
  const float* lb = (const float*)d_in[6];
  float* DU = (float*)d_out;
  float* WS = (float*)d_ws;

  xpose_chw_hwc<<<B_ * H_, 256, 0, stream>>>(x, WS);
  scnn_mfma<<<B_ / 2, 512, 0, stream>>>(WS, dw, db, rw, rb, lw, lb, DU);
  xpose_whc_chw<<<B_ * H_, 256, 0, stream>>>(WS, DU);
}